// Round 9
// baseline (126.841 us; speedup 1.0000x reference)
//
#include <hip/hip_runtime.h>

// Fused: offset = conv3x3(x,w1)+b1 ; out = deform_conv(x, offset, w2)+b2
// x: (8,3,384,384) f32 ; out: (8,3,382,382) f32
// R9: MLP push on the R8 NHWC4 structure (46.5us main, 13us transpose).
//  - phase 2 software-pipelined: prep tap k+1 (weights+addrs+issue 4 dwordx4)
//    before consuming tap k -> 8 loads in flight/wave (VGPR 36 showed the
//    compiler kept only ~4). launch_bounds(256,4): cap 64 vs natural ~55-64.
//  - transpose 4 px/thread with NT float4 plane loads: ~13 -> ~6us.
// Kept verified: NHWC4 16B corner loads (69->46.5us), XCD batch swizzle,
// e0/e1 select-folding, pk_fma pairs, NT output stores.
// R3 lesson: VGPR cap deficit must be small; watch WRITE_SIZE for spills.

#define BB 8
#define HH 384
#define WW 384
#define HO 382
#define WO 382
#define HW (HH * WW)
#define PIX_PER_BATCH (HO * WO)                              // 145924
#define BLOCKS_PER_BATCH ((PIX_PER_BATCH + 255) / 256)       // 571
#define TR_BLOCKS_PER_BATCH (HW / 1024)                      // 144 (exact)

typedef float v2f __attribute__((ext_vector_type(2), aligned(4)));
typedef float v4f __attribute__((ext_vector_type(4), aligned(16)));

static __device__ __forceinline__ v2f fma2(v2f a, v2f b, v2f c) {
    return __builtin_elementwise_fma(a, b, c);
}
static __device__ __forceinline__ v4f fma4(v4f a, v4f b, v4f c) {
    return __builtin_elementwise_fma(a, b, c);
}

// ---------------- transpose: NCHW -> NHWC4, 4 px/thread ----------------
__global__ __launch_bounds__(256) void nchw_to_nhwc4(
    const float* __restrict__ x, v4f* __restrict__ xt)
{
    const int b    = blockIdx.x & 7;          // same XCD mapping as consumer
    const int tile = blockIdx.x >> 3;
    const int p4   = tile * 256 + threadIdx.x;   // 144*256*4 == HW exactly
    const int idx  = p4 * 4;
    const float* xb = x + (long)b * 3 * HW;

    const v4f r = __builtin_nontemporal_load((const v4f*)(xb + idx));
    const v4f g = __builtin_nontemporal_load((const v4f*)(xb + HW + idx));
    const v4f bl = __builtin_nontemporal_load((const v4f*)(xb + 2 * HW + idx));

    v4f* dst = xt + (long)b * HW + idx;
    v4f o;
    o.x = r.x; o.y = g.x; o.z = bl.x; o.w = 0.f; dst[0] = o;
    o.x = r.y; o.y = g.y; o.z = bl.y;            dst[1] = o;
    o.x = r.z; o.y = g.z; o.z = bl.z;            dst[2] = o;
    o.x = r.w; o.y = g.w; o.z = bl.w;            dst[3] = o;
}

// ---------------- main fused kernel (NHWC4 input) ----------------
struct Tap {
    v4f q00, q01, q10, q11;
    float g00, g01, g10, g11;
};

__global__ __launch_bounds__(256, 4) void deform_fused_nhwc(
    const v4f* __restrict__ xt,
    const float* __restrict__ w1,
    const float* __restrict__ b1,
    const float* __restrict__ w2,
    const float* __restrict__ b2,
    float* __restrict__ out)
{
    // w1 pairs: s_w1p[((j*3+c)*9+k)*2+comp] = w1[oc=2k+comp][c][j]
    __shared__ float s_w1p[486];
    __shared__ float s_b1[18];
    __shared__ float s_w2p[54];   // pairs (o=0,1)
    __shared__ float s_w2s[27];   // scalar o=2
    __shared__ float s_b2[3];

    for (int i = threadIdx.x; i < 486; i += 256) {
        const int oc = i / 27, rem = i % 27, c = rem / 9, j = rem % 9;
        const int k = oc >> 1, comp = oc & 1;
        s_w1p[((j * 3 + c) * 9 + k) * 2 + comp] = w1[i];
    }
    if (threadIdx.x < 81) {
        const int i = threadIdx.x;
        const int o = i / 27, c = (i % 27) / 9, k = i % 9;
        if (o < 2) s_w2p[(k * 3 + c) * 2 + o] = w2[i];
        else       s_w2s[k * 3 + c] = w2[i];
    }
    if (threadIdx.x < 18) s_b1[threadIdx.x] = b1[threadIdx.x];
    if (threadIdx.x < 3)  s_b2[threadIdx.x] = b2[threadIdx.x];
    __syncthreads();

    const int b    = blockIdx.x & 7;          // XCD-locality: batch per XCD
    const int tile = blockIdx.x >> 3;
    const int idx  = tile * 256 + threadIdx.x;
    if (idx >= PIX_PER_BATCH) return;

    const int wo = idx % WO;
    const int ho = idx / WO;

    const v4f* xtb = xt + (long)b * HW;

    // ---- Phase 1: 9 (dy,dx) pairs, pixel-major, packed FMA ----
    v2f off2[9];
#pragma unroll
    for (int k = 0; k < 9; ++k) {
        v2f v; v.x = s_b1[2 * k]; v.y = s_b1[2 * k + 1];
        off2[k] = v;
    }

    const v2f* w1p = (const v2f*)s_w1p;
#pragma unroll
    for (int j = 0; j < 9; ++j) {
        const int i = j / 3, jj = j % 3;
        const v4f q = xtb[(ho + i) * WW + (wo + jj)];
#pragma unroll
        for (int c = 0; c < 3; ++c) {
            const float xc = (c == 0) ? q.x : (c == 1) ? q.y : q.z;
            v2f xcv; xcv.x = xc; xcv.y = xc;
            const v2f* wrow = w1p + (j * 3 + c) * 9;
#pragma unroll
            for (int k = 0; k < 9; ++k)
                off2[k] = fma2(xcv, wrow[k], off2[k]);
        }
    }

    // ---- Phase 2: 9 bilinear taps, software-pipelined by one tap ----
    float acc0 = s_b2[0], acc1 = s_b2[1], acc2 = s_b2[2];
    const v2f* w2p = (const v2f*)s_w2p;

    auto prep = [&](int k) -> Tap {
        const int kh = k / 3, kw = k % 3;
        v2f pos; pos.x = (float)(ho + kh); pos.y = (float)(wo + kw);
        pos += off2[k];
        const v2f fl = __builtin_elementwise_floor(pos);
        const v2f fr = pos - fl;               // (wy, wx)
        const int y0 = (int)fl.x;
        const int x0 = (int)fl.y;

        const int ry0 = min(max(y0, 0), HH - 1);
        const int ry1 = min(max(y0 + 1, 0), HH - 1);
        const int xbs = min(max(x0, 0), WW - 2);

        // validity folded into weights (matches ref: wgt * valid)
        const bool vy0 = (y0 >= 0) & (y0 <= HH - 1);
        const bool vy1 = (y0 >= -1) & (y0 <= HH - 2);
        const bool vx0 = (x0 >= 0) & (x0 <= WW - 1);
        const bool vx1 = (x0 >= -1) & (x0 <= WW - 2);
        const float wy0m = vy0 ? (1.f - fr.x) : 0.f;
        const float wy1m = vy1 ? fr.x : 0.f;
        const float wx0m = vx0 ? (1.f - fr.y) : 0.f;
        const float wx1m = vx1 ? fr.y : 0.f;

        // fold corner-column selects into (col xbs, col xbs+1) weights
        const bool selA = (x0 >= WW - 1);
        const bool selB = (x0 >= 0);
        const float e0 = (selA ? 0.f : wx0m) + (selB ? 0.f : wx1m);
        const float e1 = (selA ? wx0m : 0.f) + (selB ? wx1m : 0.f);

        Tap t;
        t.g00 = wy0m * e0; t.g01 = wy0m * e1;
        t.g10 = wy1m * e0; t.g11 = wy1m * e1;

        const int o0 = ry0 * WW + xbs;
        const int o1 = ry1 * WW + xbs;
        t.q00 = xtb[o0];
        t.q01 = xtb[o0 + 1];
        t.q10 = xtb[o1];
        t.q11 = xtb[o1 + 1];
        return t;
    };

    Tap cur = prep(0);
#pragma unroll
    for (int k = 0; k < 9; ++k) {
        Tap nxt;
        if (k < 8) nxt = prep(k + 1);

        v4f gv; gv.x = cur.g00; gv.y = cur.g00; gv.z = cur.g00; gv.w = cur.g00;
        v4f t4 = gv * cur.q00;
        gv.x = cur.g01; gv.y = cur.g01; gv.z = cur.g01; gv.w = cur.g01;
        t4 = fma4(gv, cur.q01, t4);
        gv.x = cur.g10; gv.y = cur.g10; gv.z = cur.g10; gv.w = cur.g10;
        t4 = fma4(gv, cur.q10, t4);
        gv.x = cur.g11; gv.y = cur.g11; gv.z = cur.g11; gv.w = cur.g11;
        t4 = fma4(gv, cur.q11, t4);

        const float v0 = t4.x, v1 = t4.y, v2v = t4.z;

        // epilogue: packed (acc0,acc1), scalar acc2
        v2f acc01; acc01.x = acc0; acc01.y = acc1;
        v2f vv;
        vv.x = v0;  vv.y = v0;  acc01 = fma2(vv, w2p[k * 3 + 0], acc01);
        vv.x = v1;  vv.y = v1;  acc01 = fma2(vv, w2p[k * 3 + 1], acc01);
        vv.x = v2v; vv.y = v2v; acc01 = fma2(vv, w2p[k * 3 + 2], acc01);
        acc0 = acc01.x; acc1 = acc01.y;
        acc2 = fmaf(s_w2s[k * 3 + 0], v0, acc2);
        acc2 = fmaf(s_w2s[k * 3 + 1], v1, acc2);
        acc2 = fmaf(s_w2s[k * 3 + 2], v2v, acc2);

        cur = nxt;
    }

    const long obase = ((long)(b * 3) * HO + ho) * WO + wo;
    __builtin_nontemporal_store(acc0, out + obase);
    __builtin_nontemporal_store(acc1, out + obase + (long)HO * WO);
    __builtin_nontemporal_store(acc2, out + obase + 2L * HO * WO);
}

// ---------------- fallback (R7-style, NCHW) if ws too small ----------------
__global__ __launch_bounds__(256, 6) void deform_fused_fallback(
    const float* __restrict__ x,
    const float* __restrict__ w1,
    const float* __restrict__ b1,
    const float* __restrict__ w2,
    const float* __restrict__ b2,
    float* __restrict__ out)
{
    __shared__ float s_w1p[486];
    __shared__ float s_b1[18];
    __shared__ float s_w2p[54];
    __shared__ float s_w2s[27];
    __shared__ float s_b2[3];

    for (int i = threadIdx.x; i < 486; i += 256) {
        const int oc = i / 27, rem = i % 27, c = rem / 9, j = rem % 9;
        const int k = oc >> 1, comp = oc & 1;
        s_w1p[((c * 9 + j) * 9 + k) * 2 + comp] = w1[i];
    }
    if (threadIdx.x < 81) {
        const int i = threadIdx.x;
        const int o = i / 27, c = (i % 27) / 9, k = i % 9;
        if (o < 2) s_w2p[(k * 3 + c) * 2 + o] = w2[i];
        else       s_w2s[k * 3 + c] = w2[i];
    }
    if (threadIdx.x < 18) s_b1[threadIdx.x] = b1[threadIdx.x];
    if (threadIdx.x < 3)  s_b2[threadIdx.x] = b2[threadIdx.x];
    __syncthreads();

    const int b    = blockIdx.x & 7;
    const int tile = blockIdx.x >> 3;
    const int idx  = tile * 256 + threadIdx.x;
    if (idx >= PIX_PER_BATCH) return;

    const int wo = idx % WO;
    const int ho = idx / WO;

    const float* xb = x + (long)b * 3 * HW;

    v2f off2[9];
#pragma unroll
    for (int k = 0; k < 9; ++k) {
        v2f v; v.x = s_b1[2 * k]; v.y = s_b1[2 * k + 1];
        off2[k] = v;
    }

    const v2f* w1p = (const v2f*)s_w1p;
#pragma unroll
    for (int c = 0; c < 3; ++c) {
        float xr[9];
#pragma unroll
        for (int i = 0; i < 3; ++i) {
            const float* rp = xb + c * HW + (ho + i) * WW + wo;
            const v2f p = *(const v2f*)rp;
            xr[i * 3 + 0] = p.x;
            xr[i * 3 + 1] = p.y;
            xr[i * 3 + 2] = rp[2];
        }
#pragma unroll
        for (int j = 0; j < 9; ++j) {
            v2f xj; xj.x = xr[j]; xj.y = xr[j];
            const v2f* wrow = w1p + (c * 9 + j) * 9;
#pragma unroll
            for (int k = 0; k < 9; ++k)
                off2[k] = fma2(xj, wrow[k], off2[k]);
        }
    }

    float acc0 = s_b2[0], acc1 = s_b2[1], acc2 = s_b2[2];
    const float* xc0 = xb;
    const float* xc1 = xb + HW;
    const float* xc2 = xb + 2 * HW;
    const v2f* w2p = (const v2f*)s_w2p;

#pragma unroll
    for (int k = 0; k < 9; ++k) {
        const int kh = k / 3, kw = k % 3;
        v2f pos; pos.x = (float)(ho + kh); pos.y = (float)(wo + kw);
        pos += off2[k];
        const v2f fl = __builtin_elementwise_floor(pos);
        const v2f fr = pos - fl;
        const int y0 = (int)fl.x;
        const int x0 = (int)fl.y;

        const int ry0 = min(max(y0, 0), HH - 1);
        const int ry1 = min(max(y0 + 1, 0), HH - 1);
        const int xbs = min(max(x0, 0), WW - 2);

        const bool vy0 = (y0 >= 0) & (y0 <= HH - 1);
        const bool vy1 = (y0 >= -1) & (y0 <= HH - 2);
        const bool vx0 = (x0 >= 0) & (x0 <= WW - 1);
        const bool vx1 = (x0 >= -1) & (x0 <= WW - 2);
        const float wy0m = vy0 ? (1.f - fr.x) : 0.f;
        const float wy1m = vy1 ? fr.x : 0.f;
        const float wx0m = vx0 ? (1.f - fr.y) : 0.f;
        const float wx1m = vx1 ? fr.y : 0.f;

        const bool selA = (x0 >= WW - 1);
        const bool selB = (x0 >= 0);
        const float e0 = (selA ? 0.f : wx0m) + (selB ? 0.f : wx1m);
        const float e1 = (selA ? wx0m : 0.f) + (selB ? wx1m : 0.f);
        v2f f0; f0.x = wy0m * e0; f0.y = wy0m * e1;
        v2f f1; f1.x = wy1m * e0; f1.y = wy1m * e1;

        const int o0 = ry0 * WW + xbs;
        const int o1 = ry1 * WW + xbs;

        const v2f a0 = *(const v2f*)(xc0 + o0);
        const v2f a1 = *(const v2f*)(xc0 + o1);
        const v2f b0 = *(const v2f*)(xc1 + o0);
        const v2f b1v = *(const v2f*)(xc1 + o1);
        const v2f c0 = *(const v2f*)(xc2 + o0);
        const v2f c1 = *(const v2f*)(xc2 + o1);

        const v2f t0 = fma2(f1, a1, f0 * a0);
        const v2f t1 = fma2(f1, b1v, f0 * b0);
        const v2f t2 = fma2(f1, c1, f0 * c0);
        const float v0 = t0.x + t0.y;
        const float v1 = t1.x + t1.y;
        const float v2v = t2.x + t2.y;

        v2f acc01; acc01.x = acc0; acc01.y = acc1;
        v2f vv;
        vv.x = v0;  vv.y = v0;  acc01 = fma2(vv, w2p[k * 3 + 0], acc01);
        vv.x = v1;  vv.y = v1;  acc01 = fma2(vv, w2p[k * 3 + 1], acc01);
        vv.x = v2v; vv.y = v2v; acc01 = fma2(vv, w2p[k * 3 + 2], acc01);
        acc0 = acc01.x; acc1 = acc01.y;
        acc2 = fmaf(s_w2s[k * 3 + 0], v0, acc2);
        acc2 = fmaf(s_w2s[k * 3 + 1], v1, acc2);
        acc2 = fmaf(s_w2s[k * 3 + 2], v2v, acc2);
    }

    const long obase = ((long)(b * 3) * HO + ho) * WO + wo;
    __builtin_nontemporal_store(acc0, out + obase);
    __builtin_nontemporal_store(acc1, out + obase + (long)HO * WO);
    __builtin_nontemporal_store(acc2, out + obase + 2L * HO * WO);
}

extern "C" void kernel_launch(void* const* d_in, const int* in_sizes, int n_in,
                              void* d_out, int out_size, void* d_ws, size_t ws_size,
                              hipStream_t stream) {
    const float* x  = (const float*)d_in[0];
    const float* w1 = (const float*)d_in[1];
    const float* b1 = (const float*)d_in[2];
    const float* w2 = (const float*)d_in[3];
    const float* b2 = (const float*)d_in[4];
    float* out = (float*)d_out;

    const size_t need = (size_t)BB * HW * 4 * sizeof(float);   // 18.9 MB
    if (ws_size >= need) {
        nchw_to_nhwc4<<<TR_BLOCKS_PER_BATCH * BB, 256, 0, stream>>>(x, (v4f*)d_ws);
        deform_fused_nhwc<<<BLOCKS_PER_BATCH * BB, 256, 0, stream>>>(
            (const v4f*)d_ws, w1, b1, w2, b2, out);
    } else {
        deform_fused_fallback<<<BLOCKS_PER_BATCH * BB, 256, 0, stream>>>(
            x, w1, b1, w2, b2, out);
    }
}